// Round 1
// baseline (627.193 us; speedup 1.0000x reference)
//
#include <hip/hip_runtime.h>
#include <hip/hip_fp16.h>
#include <stdint.h>

// Problem constants (B, S, H from the reference)
#define B_SZ 32
#define S_SZ 2048
#define H_SZ 1024
#define M_SZ (B_SZ * S_SZ)   // 65536 rows of the big GEMM

typedef _Float16 half8 __attribute__((ext_vector_type(8)));
typedef float floatx4 __attribute__((ext_vector_type(4)));

struct h4 { _Float16 x, y, z, w; };   // 8-byte packed fp16x4

// ---------------- fp32 -> fp16 convert (vectorized, grid-stride) ----------------
__global__ __launch_bounds__(256) void convert_f32_to_f16(
    const float* __restrict__ in, h4* __restrict__ out, int n4) {
  int i = blockIdx.x * blockDim.x + threadIdx.x;
  int stride = gridDim.x * blockDim.x;
  const float4* in4 = (const float4*)in;
  for (; i < n4; i += stride) {
    float4 f = in4[i];
    h4 o;
    o.x = (_Float16)f.x; o.y = (_Float16)f.y;
    o.z = (_Float16)f.z; o.w = (_Float16)f.w;
    out[i] = o;
  }
}

// ---------------- query = hidden @ Wq^T  (fp32 exact, tiny) ----------------
// thread t: b = t&31 (so a wave shares Wq rows -> L2-friendly), n = t>>5
__global__ __launch_bounds__(256) void query_kernel(
    const float* __restrict__ hidden, const float* __restrict__ Wq,
    float* __restrict__ q) {
  int t = blockIdx.x * blockDim.x + threadIdx.x;   // 32768 threads
  int b = t & 31;
  int n = t >> 5;
  const float4* h4p = (const float4*)(hidden + (size_t)b * H_SZ);
  const float4* w4p = (const float4*)(Wq + (size_t)n * H_SZ);
  float acc = 0.f;
  #pragma unroll 4
  for (int i = 0; i < H_SZ / 4; ++i) {
    float4 h = h4p[i], w = w4p[i];
    acc = fmaf(h.x, w.x, acc);
    acc = fmaf(h.y, w.y, acc);
    acc = fmaf(h.z, w.z, acc);
    acc = fmaf(h.w, w.w, acc);
  }
  q[(size_t)b * H_SZ + n] = acc;
}

// ---------------- async global->LDS, 16B per lane ----------------
__device__ __forceinline__ void gl_lds16(const void* g, void* l) {
  __builtin_amdgcn_global_load_lds(
      (const __attribute__((address_space(1))) void*)g,
      (__attribute__((address_space(3))) void*)l,
      16, 0, 0);
}

__device__ __forceinline__ float fast_tanh(float x) {
  float ax = fabsf(x);
  float e = __expf(ax * -2.0f);
  float t = (1.0f - e) / (1.0f + e);
  return copysignf(t, x);
}

// ---------------- fused keys-GEMM + tanh + v-dot ----------------
// C[m,n] = sum_k A[m,k] * Bt[n,k]   (A = enc fp16, Bt = Wk fp16)
// per-row partial logit: partial[bn][m] = sum_{n in col-tile} v[n]*tanh(q[b,n]+C[m,n])
#define TILE 128
#define BK 32

__global__ __launch_bounds__(256) void fused_keys_kernel(
    const _Float16* __restrict__ A,    // M_SZ x H_SZ
    const _Float16* __restrict__ Bt,   // H_SZ x H_SZ (row n = weights of output col n)
    const float* __restrict__ q,       // B_SZ x H_SZ (fp32)
    const float* __restrict__ v,       // H_SZ
    float* __restrict__ partial)       // 8 x M_SZ
{
  __shared__ _Float16 As[TILE * BK];   // 8 KB, row-major, NO padding (global_load_lds)
  __shared__ _Float16 Bs[TILE * BK];   // 8 KB
  __shared__ float rowsum[TILE];
  __shared__ float q_l[TILE];
  __shared__ float v_l[TILE];

  const int tid  = threadIdx.x;
  const int w    = tid >> 6;       // wave 0..3
  const int lane = tid & 63;
  const int bm   = blockIdx.x >> 3;   // N-major: consecutive blocks share A tile
  const int bn   = blockIdx.x & 7;
  const int R0   = bm * TILE;         // global row base (b*S + s)
  const int C0   = bn * TILE;         // global col base (n dim of H)
  const int bidx = R0 >> 11;          // batch index; uniform (2048 % 128 == 0)

  if (tid < TILE) {
    q_l[tid] = q[(size_t)bidx * H_SZ + C0 + tid];
    v_l[tid] = v[C0 + tid];
    rowsum[tid] = 0.f;
  }

  const int wm = w >> 1, wn = w & 1;   // 2x2 wave grid, each wave 64x64
  const int cL = lane & 15, quad = lane >> 4;

  floatx4 acc[4][4];
  #pragma unroll
  for (int m = 0; m < 4; ++m)
    #pragma unroll
    for (int n = 0; n < 4; ++n)
      acc[m][n] = (floatx4){0.f, 0.f, 0.f, 0.f};

  const int srow   = lane >> 2;   // 0..15: row within a 16-row staging issue
  const int schunk = lane & 3;    // 0..3: which 16B chunk of the 64B row

  const _Float16* Ablk = A + (size_t)R0 * H_SZ;
  const _Float16* Bblk = Bt + (size_t)C0 * H_SZ;

  for (int kt = 0; kt < H_SZ / BK; ++kt) {
    __syncthreads();               // previous tile's compute done before overwrite
    const int kof = kt * BK;
    #pragma unroll
    for (int r = 0; r < 2; ++r) {
      const int row = w * 16 + r * 64 + srow;
      const int ldsbase = (w * 16 + r * 64) * (BK * 2);   // bytes; + lane*16 implicit
      gl_lds16(Ablk + (size_t)row * H_SZ + kof + schunk * 8, (char*)As + ldsbase);
      gl_lds16(Bblk + (size_t)row * H_SZ + kof + schunk * 8, (char*)Bs + ldsbase);
    }
    __syncthreads();               // drain vmcnt + barrier (compiler handles)

    half8 af[4], bf[4];
    #pragma unroll
    for (int m = 0; m < 4; ++m)
      af[m] = *(const half8*)(As + (wm * 64 + m * 16 + cL) * BK + quad * 8);
    #pragma unroll
    for (int n = 0; n < 4; ++n)
      bf[n] = *(const half8*)(Bs + (wn * 64 + n * 16 + cL) * BK + quad * 8);
    #pragma unroll
    for (int m = 0; m < 4; ++m)
      #pragma unroll
      for (int n = 0; n < 4; ++n)
        acc[m][n] = __builtin_amdgcn_mfma_f32_16x16x32_f16(af[m], bf[n], acc[m][n], 0, 0, 0);
  }

  // ---- epilogue: v[n]*tanh(q+c), reduce over this block's 128 columns ----
  float qv[4], vv[4];
  #pragma unroll
  for (int n = 0; n < 4; ++n) {
    const int col = wn * 64 + n * 16 + cL;
    qv[n] = q_l[col];
    vv[n] = v_l[col];
  }
  // C/D layout: col = lane&15, row = quad*4 + reg  [m89-verified, dtype-independent]
  #pragma unroll
  for (int m = 0; m < 4; ++m) {
    #pragma unroll
    for (int r = 0; r < 4; ++r) {
      float s = 0.f;
      #pragma unroll
      for (int n = 0; n < 4; ++n)
        s += vv[n] * fast_tanh(qv[n] + acc[m][n][r]);
      // reduce across the 16 lanes (cL) sharing this row
      s += __shfl_xor(s, 1);
      s += __shfl_xor(s, 2);
      s += __shfl_xor(s, 4);
      s += __shfl_xor(s, 8);
      if (cL == 0)
        atomicAdd(&rowsum[wm * 64 + m * 16 + quad * 4 + r], s);
    }
  }
  __syncthreads();
  if (tid < TILE)
    partial[(size_t)bn * M_SZ + R0 + tid] = rowsum[tid];
}

// ---------------- masked softmax over S per batch row ----------------
__global__ __launch_bounds__(256) void softmax_kernel(
    const float* __restrict__ partial, const int* __restrict__ lengths,
    float* __restrict__ out) {
  __shared__ float wred[4];
  __shared__ float wsum[4];
  const int b = blockIdx.x;
  const int tid = threadIdx.x;
  const int len = lengths[b];

  float lg[8];
  #pragma unroll
  for (int i = 0; i < 8; ++i) {
    const int s = tid + i * 256;
    const size_t row = (size_t)b * S_SZ + s;
    float l = 0.f;
    #pragma unroll
    for (int nt = 0; nt < 8; ++nt) l += partial[(size_t)nt * M_SZ + row];
    lg[i] = (s < len) ? l : -INFINITY;
  }

  float mx = lg[0];
  #pragma unroll
  for (int i = 1; i < 8; ++i) mx = fmaxf(mx, lg[i]);
  #pragma unroll
  for (int off = 32; off; off >>= 1) mx = fmaxf(mx, __shfl_xor(mx, off));
  if ((tid & 63) == 0) wred[tid >> 6] = mx;
  __syncthreads();
  mx = fmaxf(fmaxf(wred[0], wred[1]), fmaxf(wred[2], wred[3]));

  float pe[8];
  float sum = 0.f;
  #pragma unroll
  for (int i = 0; i < 8; ++i) {
    float e = (lg[i] == -INFINITY) ? 0.f : __expf(lg[i] - mx);
    pe[i] = e;
    sum += e;
  }
  #pragma unroll
  for (int off = 32; off; off >>= 1) sum += __shfl_xor(sum, off);
  if ((tid & 63) == 0) wsum[tid >> 6] = sum;
  __syncthreads();
  sum = wsum[0] + wsum[1] + wsum[2] + wsum[3];
  const float inv = 1.0f / sum;

  #pragma unroll
  for (int i = 0; i < 8; ++i) {
    const int s = tid + i * 256;
    out[(size_t)b * S_SZ + s] = pe[i] * inv;
  }
}

extern "C" void kernel_launch(void* const* d_in, const int* in_sizes, int n_in,
                              void* d_out, int out_size, void* d_ws, size_t ws_size,
                              hipStream_t stream) {
  const float* hidden  = (const float*)d_in[0];  // (32, 1024)
  const float* enc     = (const float*)d_in[1];  // (32, 2048, 1024)
  const int*   lengths = (const int*)d_in[2];    // (32,)
  const float* Wq      = (const float*)d_in[3];  // (1024, 1024)
  const float* Wk      = (const float*)d_in[4];  // (1024, 1024)
  const float* v       = (const float*)d_in[5];  // (1024,)
  float* out = (float*)d_out;                    // (32, 2048) fp32

  // ws layout: A16 (128 MB) | B16 (2 MB) | q (128 KB) | partial (2 MB)
  char* ws = (char*)d_ws;
  _Float16* A16     = (_Float16*)ws;
  _Float16* B16     = (_Float16*)(ws + 134217728);
  float*    q       = (float*)(ws + 134217728 + 2097152);
  float*    partial = (float*)(ws + 134217728 + 2097152 + 131072);

  convert_f32_to_f16<<<8192, 256, 0, stream>>>(enc, (h4*)A16, (M_SZ * H_SZ) / 4);
  convert_f32_to_f16<<<1024, 256, 0, stream>>>(Wk, (h4*)B16, (H_SZ * H_SZ) / 4);
  query_kernel<<<128, 256, 0, stream>>>(hidden, Wq, q);
  fused_keys_kernel<<<(M_SZ / TILE) * (H_SZ / TILE), 256, 0, stream>>>(A16, B16, q, v, partial);
  softmax_kernel<<<B_SZ, 256, 0, stream>>>(partial, lengths, out);
}